// Round 2
// baseline (3545.484 us; speedup 1.0000x reference)
//
#include <hip/hip_runtime.h>

#define N_PTS 131072
#define TD 4096
#define DD 64
#define KK 1024
#define SPLITS 4
#define KS (KK / SPLITS)      // 256 codes per split
#define SCHUNK 64             // codes per LDS chunk
#define MARGIN_TH 1e-3f

// ---------------- K0: per-code half squared norms (fp64 -> fp32) ----------------
__global__ void vq_norms(const float* __restrict__ emb, float* __restrict__ halfnorm)
{
    const int k = blockIdx.x * 256 + threadIdx.x;
    if (k >= KK) return;
    const float* e = emb + (size_t)k * DD;
    double s = 0.0;
#pragma unroll
    for (int d = 0; d < DD; ++d) { double ev = (double)e[d]; s = fma(ev, ev, s); }
    halfnorm[k] = (float)(0.5 * s);
}

// ---------------- K1: fp32 screen with second-best margin, K-split x4 ----------------
__global__ __launch_bounds__(256, 4) void vq_screen(
    const float* __restrict__ z, const float* __restrict__ emb,
    const float* __restrict__ halfnorm,
    float* __restrict__ pbest, float* __restrict__ pbest2, int* __restrict__ pidx)
{
    __shared__ float4 e_lds[SCHUNK * 16];
    __shared__ float hn_s[SCHUNK];
    const int tid = threadIdx.x;
    const int split = blockIdx.x & (SPLITS - 1);
    const int pb = blockIdx.x >> 2;
    const int n = pb * 256 + tid;
    const int b = n >> 12;
    const int t = n & 4095;
    const float* zb = z + ((size_t)b * DD) * TD + t;

    float zr[DD];
#pragma unroll
    for (int d = 0; d < DD; ++d) zr[d] = zb[(size_t)d * TD];

    float best = 1e30f, best2 = 1e30f;
    int bi = 0;

    for (int c = 0; c < KS / SCHUNK; ++c) {
        const int kbase = split * KS + c * SCHUNK;
        __syncthreads();
        const float4* esrc = (const float4*)(emb + (size_t)kbase * DD);
        for (int i = tid; i < SCHUNK * 16; i += 256) e_lds[i] = esrc[i];
        if (tid < SCHUNK) hn_s[tid] = halfnorm[kbase + tid];
        __syncthreads();

        for (int kk = 0; kk < SCHUNK; ++kk) {
            const float4* ep = &e_lds[kk * 16];
            float a0 = 0.f, a1 = 0.f, a2 = 0.f, a3 = 0.f;
#pragma unroll
            for (int j = 0; j < 16; ++j) {
                float4 e = ep[j];
                a0 = fmaf(zr[4 * j + 0], e.x, a0);
                a1 = fmaf(zr[4 * j + 1], e.y, a1);
                a2 = fmaf(zr[4 * j + 2], e.z, a2);
                a3 = fmaf(zr[4 * j + 3], e.w, a3);
            }
            float s = hn_s[kk] - ((a0 + a1) + (a2 + a3));
            best2 = fminf(best2, fmaxf(best, s));
            if (s < best) { best = s; bi = kbase + kk; }
        }
    }

    pbest[(size_t)split * N_PTS + n] = best;
    pbest2[(size_t)split * N_PTS + n] = best2;
    pidx[(size_t)split * N_PTS + n] = bi;
}

// ---------------- K1b: merge splits, flag near-ties, scatter confident points ----------------
__global__ __launch_bounds__(256) void vq_merge(
    const float* __restrict__ z,
    const float* __restrict__ pbest, const float* __restrict__ pbest2,
    const int* __restrict__ pidx,
    int* __restrict__ idx_ws, float* __restrict__ ind_out,
    float* __restrict__ counts, float* __restrict__ esum,
    int* __restrict__ nflag, int* __restrict__ flags)
{
    const int n = blockIdx.x * 256 + threadIdx.x;
    float best = 1e30f, best2 = 1e30f;
    int bi = 0;
#pragma unroll
    for (int s = 0; s < SPLITS; ++s) {
        float b  = pbest[(size_t)s * N_PTS + n];
        float b2 = pbest2[(size_t)s * N_PTS + n];
        int  ix  = pidx[(size_t)s * N_PTS + n];
        if (b < best) { best2 = fminf(best, b2); best = b; bi = ix; }
        else          { best2 = fminf(best2, b); }
    }
    idx_ws[n] = bi;
    ind_out[n] = (float)bi;
    if (best2 - best < MARGIN_TH) {
        int pos = atomicAdd(nflag, 1);
        flags[pos] = n;          // exact fp64 pass will finalize + scatter this point
        return;
    }
    const int b_ = n >> 12, t_ = n & 4095;
    const float* zb = z + ((size_t)b_ * DD) * TD + t_;
    atomicAdd(&counts[bi], 1.0f);
    float* row = esum + (size_t)bi * DD;
#pragma unroll
    for (int d = 0; d < DD; ++d) atomicAdd(&row[d], zb[(size_t)d * TD]);
}

// ---------------- K1c: fp64 exact rescan for near-tie points ----------------
__global__ __launch_bounds__(64) void vq_fallback(
    const float* __restrict__ z, const float* __restrict__ emb,
    int* __restrict__ idx_ws, float* __restrict__ ind_out,
    float* __restrict__ counts, float* __restrict__ esum,
    const int* __restrict__ nflag, const int* __restrict__ flags)
{
    const int total = *nflag;
    for (int i = blockIdx.x * 64 + threadIdx.x; i < total; i += gridDim.x * 64) {
        const int n = flags[i];
        const int b = n >> 12, t = n & 4095;
        const float* zb = z + ((size_t)b * DD) * TD + t;
        double zr[DD];
#pragma unroll
        for (int d = 0; d < DD; ++d) zr[d] = (double)zb[(size_t)d * TD];
        double best = 1e300;
        int bi = 0;
        for (int k = 0; k < KK; ++k) {
            const float* e = emb + (size_t)k * DD;
            double dot = 0.0, nn = 0.0;
#pragma unroll
            for (int d = 0; d < DD; ++d) {
                double ev = (double)e[d];
                nn = fma(ev, ev, nn);
                dot = fma(zr[d], ev, dot);
            }
            double s = 0.5 * nn - dot;
            if (s < best) { best = s; bi = k; }
        }
        idx_ws[n] = bi;
        ind_out[n] = (float)bi;
        atomicAdd(&counts[bi], 1.0f);
        float* row = esum + (size_t)bi * DD;
#pragma unroll
        for (int d = 0; d < DD; ++d) atomicAdd(&row[d], (float)zr[d]);
    }
}

// ---------------- K2: EMA update + Laplace smoothing + new embedding ----------------
__global__ __launch_bounds__(1024) void vq_update(
    const float* __restrict__ cs, const float* __restrict__ counts,
    const float* __restrict__ avg, const float* __restrict__ esum,
    float* __restrict__ newE)
{
    __shared__ double red[1024];
    __shared__ float smo[1024];
    const int k = threadIdx.x;
    const double DECAY = 0.99, OMD = 1.0 - 0.99, EPSV = 1e-5;
    double ncs = DECAY * (double)cs[k] + OMD * (double)counts[k];
    red[k] = ncs;
    __syncthreads();
    for (int s = 512; s > 0; s >>= 1) {
        if (k < s) red[k] += red[k + s];
        __syncthreads();
    }
    double nsum = red[0];
    smo[k] = (float)((ncs + EPSV) / (nsum + (double)KK * EPSV) * nsum);
    __syncthreads();
    for (int it = 0; it < DD; ++it) {
        int j = it * 1024 + k;
        int kk = j >> 6;
        newE[j] = (float)((DECAY * (double)avg[j] + OMD * (double)esum[j]) / (double)smo[kk]);
    }
}

// ---------------- K3: gather z_q + commitment loss ----------------
__global__ __launch_bounds__(256) void vq_gather_loss(
    const float* __restrict__ z, const float* __restrict__ newE,
    const int* __restrict__ idx_ws, float* __restrict__ zq_out,
    double* __restrict__ loss_acc)
{
    const int tid = threadIdx.x;
    const int n = blockIdx.x * 256 + tid;
    const int b = n >> 12;
    const int t = n & 4095;
    const float* zb = z + ((size_t)b * DD) * TD + t;
    float* ob = zq_out + ((size_t)b * DD) * TD + t;
    const int bi = idx_ws[n];
    const float* e = newE + (size_t)bi * DD;
    double acc = 0.0;
#pragma unroll
    for (int d = 0; d < DD; ++d) {
        float q = e[d];
        float zv = zb[(size_t)d * TD];
        ob[(size_t)d * TD] = q;
        float df = zv - q;
        acc = fma((double)df, (double)df, acc);
    }
    for (int off = 32; off > 0; off >>= 1) acc += __shfl_down(acc, off, 64);
    __shared__ double wsum[4];
    const int wid = tid >> 6, lane = tid & 63;
    if (lane == 0) wsum[wid] = acc;
    __syncthreads();
    if (tid == 0) atomicAdd(loss_acc, wsum[0] + wsum[1] + wsum[2] + wsum[3]);
}

// ---------------- K4: finalize loss ----------------
__global__ void vq_finalize(const double* __restrict__ loss_acc, float* __restrict__ loss_out)
{
    *loss_out = (float)(0.25 * (*loss_acc) / (double)(N_PTS * DD));
}

extern "C" void kernel_launch(void* const* d_in, const int* in_sizes, int n_in,
                              void* d_out, int out_size, void* d_ws, size_t ws_size,
                              hipStream_t stream) {
    const float* z    = (const float*)d_in[0];   // [32, 64, 4096]
    const float* emb  = (const float*)d_in[1];   // [1024, 64]
    const float* cs   = (const float*)d_in[2];   // [1024]
    const float* avg  = (const float*)d_in[3];   // [1024, 64]

    float* out      = (float*)d_out;
    float* zq_out   = out;                // 8388608 floats
    float* loss_out = out + 8388608;      // 1
    float* ind_out  = out + 8388609;      // 131072 (indices as float)

    // Scratch inside the z_q region of d_out (dead before K3 rewrites all of it)
    float* pbest  = out;                         // 4*131072 floats
    float* pbest2 = out + 524288;                // 4*131072 floats
    int*   pidx   = (int*)out + 1048576;         // 4*131072 ints
    int*   flags  = (int*)out + 1572864;         // up to 131072 ints

    char* ws = (char*)d_ws;
    int*    idx_ws   = (int*)ws;                     // 512 KB
    float*  newE     = (float*)(ws + 524288);        // 256 KB
    float*  counts   = (float*)(ws + 786432);        // 4 KB
    float*  esum     = (float*)(ws + 790528);        // 256 KB
    double* loss_acc = (double*)(ws + 1052672);      // 8 B
    int*    nflag    = (int*)(ws + 1052680);         // 4 B (+4 pad)
    float*  halfnorm = (float*)(ws + 1052688);       // 4 KB

    // zero counts + esum + loss_acc + nflag (contiguous)
    hipMemsetAsync(ws + 786432, 0, 4096 + 262144 + 16, stream);

    vq_norms<<<4, 256, 0, stream>>>(emb, halfnorm);
    vq_screen<<<(N_PTS / 256) * SPLITS, 256, 0, stream>>>(z, emb, halfnorm, pbest, pbest2, pidx);
    vq_merge<<<N_PTS / 256, 256, 0, stream>>>(z, pbest, pbest2, pidx, idx_ws, ind_out,
                                              counts, esum, nflag, flags);
    vq_fallback<<<256, 64, 0, stream>>>(z, emb, idx_ws, ind_out, counts, esum, nflag, flags);
    vq_update<<<1, 1024, 0, stream>>>(cs, counts, avg, esum, newE);
    vq_gather_loss<<<N_PTS / 256, 256, 0, stream>>>(z, newE, idx_ws, zq_out, loss_acc);
    vq_finalize<<<1, 1, 0, stream>>>(loss_acc, loss_out);
}

// Round 3
// 2121.362 us; speedup vs baseline: 1.6713x; 1.6713x over previous
//
#include <hip/hip_runtime.h>

#define N_PTS 131072
#define TD 4096
#define DD 64
#define KK 1024
#define SPLITS 4
#define KS (KK / SPLITS)      // 256 codes per split
#define SCHUNK 64             // codes per LDS chunk
#define MARGIN_TH 1e-3f

// ---------------- K0: per-code half squared norms (fp64 -> fp32) ----------------
__global__ void vq_norms(const float* __restrict__ emb, float* __restrict__ halfnorm)
{
    const int k = blockIdx.x * 256 + threadIdx.x;
    if (k >= KK) return;
    const float* e = emb + (size_t)k * DD;
    double s = 0.0;
#pragma unroll
    for (int d = 0; d < DD; ++d) { double ev = (double)e[d]; s = fma(ev, ev, s); }
    halfnorm[k] = (float)(0.5 * s);
}

// ---------------- K1: fp32 screen with second-best margin, K-split x4 ----------------
__global__ __launch_bounds__(256, 4) void vq_screen(
    const float* __restrict__ z, const float* __restrict__ emb,
    const float* __restrict__ halfnorm,
    float* __restrict__ pbest, float* __restrict__ pbest2, int* __restrict__ pidx)
{
    __shared__ float4 e_lds[SCHUNK * 16];
    __shared__ float hn_s[SCHUNK];
    const int tid = threadIdx.x;
    const int split = blockIdx.x & (SPLITS - 1);
    const int pb = blockIdx.x >> 2;
    const int n = pb * 256 + tid;
    const int b = n >> 12;
    const int t = n & 4095;
    const float* zb = z + ((size_t)b * DD) * TD + t;

    float zr[DD];
#pragma unroll
    for (int d = 0; d < DD; ++d) zr[d] = zb[(size_t)d * TD];

    float best = 1e30f, best2 = 1e30f;
    int bi = 0;

    for (int c = 0; c < KS / SCHUNK; ++c) {
        const int kbase = split * KS + c * SCHUNK;
        __syncthreads();
        const float4* esrc = (const float4*)(emb + (size_t)kbase * DD);
        for (int i = tid; i < SCHUNK * 16; i += 256) e_lds[i] = esrc[i];
        if (tid < SCHUNK) hn_s[tid] = halfnorm[kbase + tid];
        __syncthreads();

        // two codes per iteration: 8 independent FMA chains
        for (int kk = 0; kk < SCHUNK; kk += 2) {
            const float4* ep0 = &e_lds[kk * 16];
            const float4* ep1 = &e_lds[kk * 16 + 16];
            float a0 = 0.f, a1 = 0.f, a2 = 0.f, a3 = 0.f;
            float b0 = 0.f, b1 = 0.f, b2 = 0.f, b3 = 0.f;
#pragma unroll
            for (int j = 0; j < 16; ++j) {
                float4 e0 = ep0[j];
                float4 e1 = ep1[j];
                a0 = fmaf(zr[4 * j + 0], e0.x, a0);
                a1 = fmaf(zr[4 * j + 1], e0.y, a1);
                a2 = fmaf(zr[4 * j + 2], e0.z, a2);
                a3 = fmaf(zr[4 * j + 3], e0.w, a3);
                b0 = fmaf(zr[4 * j + 0], e1.x, b0);
                b1 = fmaf(zr[4 * j + 1], e1.y, b1);
                b2 = fmaf(zr[4 * j + 2], e1.z, b2);
                b3 = fmaf(zr[4 * j + 3], e1.w, b3);
            }
            float s0 = hn_s[kk]     - ((a0 + a1) + (a2 + a3));
            float s1 = hn_s[kk + 1] - ((b0 + b1) + (b2 + b3));
            best2 = fminf(best2, fmaxf(best, s0));
            if (s0 < best) { best = s0; bi = kbase + kk; }
            best2 = fminf(best2, fmaxf(best, s1));
            if (s1 < best) { best = s1; bi = kbase + kk + 1; }
        }
    }

    pbest[(size_t)split * N_PTS + n] = best;
    pbest2[(size_t)split * N_PTS + n] = best2;
    pidx[(size_t)split * N_PTS + n] = bi;
}

// ---------------- K1b: merge splits, flag near-ties (NO heavy atomics) ----------------
__global__ __launch_bounds__(256) void vq_merge(
    const float* __restrict__ pbest, const float* __restrict__ pbest2,
    const int* __restrict__ pidx,
    int* __restrict__ idx_ws, float* __restrict__ ind_out,
    int* __restrict__ nflag, int* __restrict__ flags)
{
    const int n = blockIdx.x * 256 + threadIdx.x;
    float best = 1e30f, best2 = 1e30f;
    int bi = 0;
#pragma unroll
    for (int s = 0; s < SPLITS; ++s) {
        float b  = pbest[(size_t)s * N_PTS + n];
        float b2 = pbest2[(size_t)s * N_PTS + n];
        int  ix  = pidx[(size_t)s * N_PTS + n];
        if (b < best) { best2 = fminf(best, b2); best = b; bi = ix; }
        else          { best2 = fminf(best2, b); }
    }
    idx_ws[n] = bi;            // provisional for flagged points; fallback overwrites
    ind_out[n] = (float)bi;

    const bool flag = (best2 - best < MARGIN_TH);
    const unsigned long long m = __ballot(flag);
    const int lane = threadIdx.x & 63;
    const int cnt = __popcll(m);
    int base = 0;
    if (cnt) {
        if (lane == 0) base = atomicAdd(nflag, cnt);
        base = __shfl(base, 0, 64);
        if (flag) {
            int off = __popcll(m & ((1ull << lane) - 1ull));
            flags[base + off] = n;
        }
    }
}

// ---------------- K1c: fp64 exact rescan for near-tie points (wave per point) ----------------
__global__ __launch_bounds__(256) void vq_fallback(
    const float* __restrict__ z, const float* __restrict__ emb,
    int* __restrict__ idx_ws, float* __restrict__ ind_out,
    const int* __restrict__ nflag, const int* __restrict__ flags)
{
    __shared__ float zs[4][DD];
    const int total = *nflag;
    const int lane = threadIdx.x & 63;
    const int wid = threadIdx.x >> 6;
    const int gw = blockIdx.x * 4 + wid;

    for (int i = gw; i < total; i += gridDim.x * 4) {
        const int n = flags[i];
        const int b = n >> 12, t = n & 4095;
        zs[wid][lane] = z[((size_t)b * DD + lane) * TD + t];
        __builtin_amdgcn_s_waitcnt(0);  // lgkmcnt(0) for LDS write visibility in-wave
        double best = 1e300;
        int bi = KK;
        for (int kc = 0; kc < KK / 64; ++kc) {
            const int k = kc * 64 + lane;
            const float4* e = (const float4*)(emb + (size_t)k * DD);
            double dot = 0.0, nn = 0.0;
#pragma unroll
            for (int j = 0; j < 16; ++j) {
                float4 ev = e[j];
                double e0 = (double)ev.x, e1 = (double)ev.y, e2 = (double)ev.z, e3 = (double)ev.w;
                nn = fma(e0, e0, fma(e1, e1, fma(e2, e2, fma(e3, e3, nn))));
                dot = fma((double)zs[wid][4 * j + 0], e0,
                      fma((double)zs[wid][4 * j + 1], e1,
                      fma((double)zs[wid][4 * j + 2], e2,
                      fma((double)zs[wid][4 * j + 3], e3, dot))));
            }
            double s = 0.5 * nn - dot;
            if (s < best || (s == best && k < bi)) { best = s; bi = k; }
        }
        // wave argmin-reduce with index tie-break (numpy first-min semantics)
        for (int off = 32; off > 0; off >>= 1) {
            double os = __shfl_down(best, off, 64);
            int oi = __shfl_down(bi, off, 64);
            if (os < best || (os == best && oi < bi)) { best = os; bi = oi; }
        }
        if (lane == 0) { idx_ws[n] = bi; ind_out[n] = (float)bi; }
    }
}

// ---------------- K2a: histogram of final indices (LDS-privatized) ----------------
__global__ __launch_bounds__(256) void vq_hist(const int* __restrict__ idx_ws, int* __restrict__ hist)
{
    __shared__ int h[KK];
    for (int i = threadIdx.x; i < KK; i += 256) h[i] = 0;
    __syncthreads();
    const int base = blockIdx.x * 2048;
#pragma unroll
    for (int j = 0; j < 8; ++j)
        atomicAdd(&h[idx_ws[base + j * 256 + threadIdx.x]], 1);
    __syncthreads();
    for (int i = threadIdx.x; i < KK; i += 256)
        if (h[i]) atomicAdd(&hist[i], h[i]);
}

// ---------------- K2b: exclusive scan -> start/cursor ----------------
__global__ __launch_bounds__(1024) void vq_prefix(const int* __restrict__ hist,
                                                  int* __restrict__ start, int* __restrict__ cursor)
{
    __shared__ int tmp[KK];
    const int k = threadIdx.x;
    const int c = hist[k];
    tmp[k] = c;
    __syncthreads();
    for (int off = 1; off < KK; off <<= 1) {
        int u = (k >= off) ? tmp[k - off] : 0;
        __syncthreads();
        tmp[k] += u;
        __syncthreads();
    }
    const int s = tmp[k] - c;  // exclusive
    start[k] = s;
    cursor[k] = s;
}

// ---------------- K2c: scatter point ids into per-code lists ----------------
__global__ __launch_bounds__(256) void vq_scatter(const int* __restrict__ idx_ws,
                                                  int* __restrict__ cursor, int* __restrict__ order)
{
    const int n = blockIdx.x * 256 + threadIdx.x;
    const int bi = idx_ws[n];
    const int pos = atomicAdd(&cursor[bi], 1);
    order[pos] = n;
}

// ---------------- K2d: segment sum per code (block per code, fp64 acc) ----------------
__global__ __launch_bounds__(256) void vq_esum(
    const float* __restrict__ z, const int* __restrict__ order,
    const int* __restrict__ start, const int* __restrict__ hist,
    float* __restrict__ esum)
{
    const int k = blockIdx.x;
    const int d = threadIdx.x & 63;
    const int sub = threadIdx.x >> 6;
    const int s0 = start[k], cnt = hist[k];
    double acc = 0.0;
    for (int i = sub; i < cnt; i += 4) {
        const int n = order[s0 + i];
        const int b = n >> 12, t = n & 4095;
        acc += (double)z[((size_t)b * DD + d) * TD + t];
    }
    __shared__ double red[4][DD];
    red[sub][d] = acc;
    __syncthreads();
    if (sub == 0)
        esum[(size_t)k * DD + d] = (float)(red[0][d] + red[1][d] + red[2][d] + red[3][d]);
}

// ---------------- K3: EMA update + Laplace smoothing + new embedding ----------------
__global__ __launch_bounds__(1024) void vq_update(
    const float* __restrict__ cs, const int* __restrict__ hist,
    const float* __restrict__ avg, const float* __restrict__ esum,
    float* __restrict__ newE)
{
    __shared__ double red[KK];
    __shared__ float smo[KK];
    const int k = threadIdx.x;
    const double DECAY = 0.99, OMD = 1.0 - 0.99, EPSV = 1e-5;
    double ncs = DECAY * (double)cs[k] + OMD * (double)hist[k];
    red[k] = ncs;
    __syncthreads();
    for (int s = 512; s > 0; s >>= 1) {
        if (k < s) red[k] += red[k + s];
        __syncthreads();
    }
    double nsum = red[0];
    smo[k] = (float)((ncs + EPSV) / (nsum + (double)KK * EPSV) * nsum);
    __syncthreads();
    for (int it = 0; it < DD; ++it) {
        int j = it * KK + k;
        int kk = j >> 6;
        newE[j] = (float)((DECAY * (double)avg[j] + OMD * (double)esum[j]) / (double)smo[kk]);
    }
}

// ---------------- K4: gather z_q + commitment loss ----------------
__global__ __launch_bounds__(256) void vq_gather_loss(
    const float* __restrict__ z, const float* __restrict__ newE,
    const int* __restrict__ idx_ws, float* __restrict__ zq_out,
    double* __restrict__ loss_acc)
{
    const int tid = threadIdx.x;
    const int n = blockIdx.x * 256 + tid;
    const int b = n >> 12;
    const int t = n & 4095;
    const float* zb = z + ((size_t)b * DD) * TD + t;
    float* ob = zq_out + ((size_t)b * DD) * TD + t;
    const int bi = idx_ws[n];
    const float* e = newE + (size_t)bi * DD;
    double acc = 0.0;
#pragma unroll
    for (int d = 0; d < DD; ++d) {
        float q = e[d];
        float zv = zb[(size_t)d * TD];
        ob[(size_t)d * TD] = q;
        float df = zv - q;
        acc = fma((double)df, (double)df, acc);
    }
    for (int off = 32; off > 0; off >>= 1) acc += __shfl_down(acc, off, 64);
    __shared__ double wsum[4];
    const int wid = tid >> 6, lane = tid & 63;
    if (lane == 0) wsum[wid] = acc;
    __syncthreads();
    if (tid == 0) atomicAdd(loss_acc, wsum[0] + wsum[1] + wsum[2] + wsum[3]);
}

// ---------------- K5: finalize loss ----------------
__global__ void vq_finalize(const double* __restrict__ loss_acc, float* __restrict__ loss_out)
{
    *loss_out = (float)(0.25 * (*loss_acc) / (double)(N_PTS * DD));
}

extern "C" void kernel_launch(void* const* d_in, const int* in_sizes, int n_in,
                              void* d_out, int out_size, void* d_ws, size_t ws_size,
                              hipStream_t stream) {
    const float* z    = (const float*)d_in[0];   // [32, 64, 4096]
    const float* emb  = (const float*)d_in[1];   // [1024, 64]
    const float* cs   = (const float*)d_in[2];   // [1024]
    const float* avg  = (const float*)d_in[3];   // [1024, 64]

    float* out      = (float*)d_out;
    float* zq_out   = out;                // 8388608 floats
    float* loss_out = out + 8388608;      // 1
    float* ind_out  = out + 8388609;      // 131072 (indices as float)

    // Scratch inside the z_q region of d_out (all dead before K4 rewrites it)
    float* pbest  = out;                         // 4*131072 floats
    float* pbest2 = out + 524288;                // 4*131072 floats
    int*   pidx   = (int*)out + 1048576;         // 4*131072 ints
    int*   flags  = (int*)out + 1572864;         // up to 131072 ints
    int*   order  = (int*)out + 1703936;         // 131072 ints

    char* ws = (char*)d_ws;
    int*    idx_ws   = (int*)ws;                     // 512 KB @ 0
    float*  newE     = (float*)(ws + 524288);        // 256 KB
    float*  esum     = (float*)(ws + 786432);        // 256 KB
    int*    hist     = (int*)(ws + 1048576);         // 4 KB   [memset]
    int*    nflag    = (int*)(ws + 1052672);         // 4 B    [memset]
    double* loss_acc = (double*)(ws + 1052680);      // 8 B    [memset]
    float*  halfnorm = (float*)(ws + 1052688);       // 4 KB
    int*    start    = (int*)(ws + 1056784);         // 4 KB
    int*    cursor   = (int*)(ws + 1060880);         // 4 KB

    // zero hist + nflag + pad + loss_acc (contiguous 4112 B)
    hipMemsetAsync(ws + 1048576, 0, 4112, stream);

    vq_norms<<<4, 256, 0, stream>>>(emb, halfnorm);
    vq_screen<<<(N_PTS / 256) * SPLITS, 256, 0, stream>>>(z, emb, halfnorm, pbest, pbest2, pidx);
    vq_merge<<<N_PTS / 256, 256, 0, stream>>>(pbest, pbest2, pidx, idx_ws, ind_out, nflag, flags);
    vq_fallback<<<128, 256, 0, stream>>>(z, emb, idx_ws, ind_out, nflag, flags);
    vq_hist<<<64, 256, 0, stream>>>(idx_ws, hist);
    vq_prefix<<<1, 1024, 0, stream>>>(hist, start, cursor);
    vq_scatter<<<N_PTS / 256, 256, 0, stream>>>(idx_ws, cursor, order);
    vq_esum<<<KK, 256, 0, stream>>>(z, order, start, hist, esum);
    vq_update<<<1, 1024, 0, stream>>>(cs, hist, avg, esum, newE);
    vq_gather_loss<<<N_PTS / 256, 256, 0, stream>>>(z, newE, idx_ws, zq_out, loss_acc);
    vq_finalize<<<1, 1, 0, stream>>>(loss_acc, loss_out);
}

// Round 4
// 1037.237 us; speedup vs baseline: 3.4182x; 2.0452x over previous
//
#include <hip/hip_runtime.h>

#define N_PTS 131072
#define TD 4096
#define DD 64
#define KK 1024
#define SCHUNK 64             // codes per LDS chunk
#define MARGIN_TH 1e-3f

// ---------------- K0a: tiled transpose z[B,D,T] -> z_flat[N,D] ----------------
// block = (b, t-tile of 64); 256 threads
__global__ __launch_bounds__(256) void vq_transpose(const float* __restrict__ z,
                                                    float* __restrict__ zf)
{
    __shared__ float tile[64][65];
    const int tid = threadIdx.x;
    const int lane = tid & 63;
    const int sub = tid >> 6;           // 0..3
    const int b = blockIdx.x >> 6;      // 32 b
    const int t0 = (blockIdx.x & 63) * 64;
#pragma unroll
    for (int i = 0; i < 16; ++i) {
        const int d = i * 4 + sub;
        tile[lane][d] = z[((size_t)b * DD + d) * TD + t0 + lane];
    }
    __syncthreads();
#pragma unroll
    for (int i = 0; i < 16; ++i) {
        const int tl = i * 4 + sub;
        zf[((size_t)(b * TD + t0 + tl)) * DD + lane] = tile[tl][lane];
    }
}

// ---------------- K0b: per-code half squared norms (fp64 -> fp32) ----------------
__global__ void vq_norms(const float* __restrict__ emb, float* __restrict__ halfnorm)
{
    const int k = blockIdx.x * 256 + threadIdx.x;
    if (k >= KK) return;
    const float* e = emb + (size_t)k * DD;
    double s = 0.0;
#pragma unroll
    for (int d = 0; d < DD; ++d) { double ev = (double)e[d]; s = fma(ev, ev, s); }
    halfnorm[k] = (float)(0.5 * s);
}

// ---------------- K1: fp32 screen, all 1024 codes, flag near-ties ----------------
__global__ __launch_bounds__(256, 2) void vq_screen(
    const float* __restrict__ z, const float* __restrict__ emb,
    const float* __restrict__ halfnorm,
    int* __restrict__ idx_ws, float* __restrict__ ind_out,
    int* __restrict__ nflag, int* __restrict__ flags)
{
    __shared__ float4 e_lds[SCHUNK * 16];
    __shared__ float hn_s[SCHUNK];
    const int tid = threadIdx.x;
    const int n = blockIdx.x * 256 + tid;
    const int b = n >> 12;
    const int t = n & 4095;
    const float* zb = z + ((size_t)b * DD) * TD + t;

    float zr[DD];
#pragma unroll
    for (int d = 0; d < DD; ++d) zr[d] = zb[(size_t)d * TD];

    float best = 1e30f, best2 = 1e30f;
    int bi = 0;

    for (int c = 0; c < KK / SCHUNK; ++c) {
        const int kbase = c * SCHUNK;
        __syncthreads();
        const float4* esrc = (const float4*)(emb + (size_t)kbase * DD);
        for (int i = tid; i < SCHUNK * 16; i += 256) e_lds[i] = esrc[i];
        if (tid < SCHUNK) hn_s[tid] = halfnorm[kbase + tid];
        __syncthreads();

        for (int kk = 0; kk < SCHUNK; ++kk) {
            const float4* ep = &e_lds[kk * 16];
            float a0 = 0.f, a1 = 0.f, a2 = 0.f, a3 = 0.f;
#pragma unroll
            for (int j = 0; j < 16; ++j) {
                float4 e = ep[j];
                a0 = fmaf(zr[4 * j + 0], e.x, a0);
                a1 = fmaf(zr[4 * j + 1], e.y, a1);
                a2 = fmaf(zr[4 * j + 2], e.z, a2);
                a3 = fmaf(zr[4 * j + 3], e.w, a3);
            }
            float s = hn_s[kk] - ((a0 + a1) + (a2 + a3));
            best2 = fminf(best2, fmaxf(best, s));
            if (s < best) { best = s; bi = kbase + kk; }
        }
    }

    idx_ws[n] = bi;            // provisional for flagged points; fallback overwrites
    ind_out[n] = (float)bi;

    const bool flag = (best2 - best < MARGIN_TH);
    const unsigned long long m = __ballot(flag);
    const int lane = tid & 63;
    const int cnt = __popcll(m);
    int base = 0;
    if (cnt) {
        if (lane == 0) base = atomicAdd(nflag, cnt);
        base = __shfl(base, 0, 64);
        if (flag) {
            int off = __popcll(m & ((1ull << lane) - 1ull));
            flags[base + off] = n;
        }
    }
}

// ---------------- K1c: fp64 exact rescan for near-tie points (wave per point) ----------------
__global__ __launch_bounds__(256) void vq_fallback(
    const float* __restrict__ zf, const float* __restrict__ emb,
    int* __restrict__ idx_ws, float* __restrict__ ind_out,
    const int* __restrict__ nflag, const int* __restrict__ flags)
{
    __shared__ float zs[4][DD];
    const int total = *nflag;
    const int lane = threadIdx.x & 63;
    const int wid = threadIdx.x >> 6;
    const int gw = blockIdx.x * 4 + wid;

    for (int i = gw; i < total; i += gridDim.x * 4) {
        const int n = flags[i];
        zs[wid][lane] = zf[(size_t)n * DD + lane];
        __builtin_amdgcn_s_waitcnt(0);
        double best = 1e300;
        int bi = KK;
        for (int kc = 0; kc < KK / 64; ++kc) {
            const int k = kc * 64 + lane;
            const float4* e = (const float4*)(emb + (size_t)k * DD);
            double dot = 0.0, nn = 0.0;
#pragma unroll
            for (int j = 0; j < 16; ++j) {
                float4 ev = e[j];
                double e0 = (double)ev.x, e1 = (double)ev.y, e2 = (double)ev.z, e3 = (double)ev.w;
                nn = fma(e0, e0, fma(e1, e1, fma(e2, e2, fma(e3, e3, nn))));
                dot = fma((double)zs[wid][4 * j + 0], e0,
                      fma((double)zs[wid][4 * j + 1], e1,
                      fma((double)zs[wid][4 * j + 2], e2,
                      fma((double)zs[wid][4 * j + 3], e3, dot))));
            }
            double s = 0.5 * nn - dot;
            if (s < best || (s == best && k < bi)) { best = s; bi = k; }
        }
        for (int off = 32; off > 0; off >>= 1) {
            double os = __shfl_down(best, off, 64);
            int oi = __shfl_down(bi, off, 64);
            if (os < best || (os == best && oi < bi)) { best = os; bi = oi; }
        }
        if (lane == 0) { idx_ws[n] = bi; ind_out[n] = (float)bi; }
    }
}

// ---------------- K2a: histogram of final indices (LDS-privatized) ----------------
__global__ __launch_bounds__(256) void vq_hist(const int* __restrict__ idx_ws, int* __restrict__ hist)
{
    __shared__ int h[KK];
    for (int i = threadIdx.x; i < KK; i += 256) h[i] = 0;
    __syncthreads();
    const int base = blockIdx.x * 2048;
#pragma unroll
    for (int j = 0; j < 8; ++j)
        atomicAdd(&h[idx_ws[base + j * 256 + threadIdx.x]], 1);
    __syncthreads();
    for (int i = threadIdx.x; i < KK; i += 256)
        if (h[i]) atomicAdd(&hist[i], h[i]);
}

// ---------------- K2b: exclusive scan -> start/cursor ----------------
__global__ __launch_bounds__(1024) void vq_prefix(const int* __restrict__ hist,
                                                  int* __restrict__ start, int* __restrict__ cursor)
{
    __shared__ int tmp[KK];
    const int k = threadIdx.x;
    const int c = hist[k];
    tmp[k] = c;
    __syncthreads();
    for (int off = 1; off < KK; off <<= 1) {
        int u = (k >= off) ? tmp[k - off] : 0;
        __syncthreads();
        tmp[k] += u;
        __syncthreads();
    }
    const int s = tmp[k] - c;  // exclusive
    start[k] = s;
    cursor[k] = s;
}

// ---------------- K2c: scatter point ids into per-code lists ----------------
__global__ __launch_bounds__(256) void vq_scatter(const int* __restrict__ idx_ws,
                                                  int* __restrict__ cursor, int* __restrict__ order)
{
    const int n = blockIdx.x * 256 + threadIdx.x;
    const int bi = idx_ws[n];
    const int pos = atomicAdd(&cursor[bi], 1);
    order[pos] = n;
}

// ---------------- K2d: segment sum per code from z_flat (block per code, fp64 acc) ----------------
__global__ __launch_bounds__(256) void vq_esum(
    const float* __restrict__ zf, const int* __restrict__ order,
    const int* __restrict__ start, const int* __restrict__ hist,
    float* __restrict__ esum)
{
    const int k = blockIdx.x;
    const int d = threadIdx.x & 63;
    const int sub = threadIdx.x >> 6;
    const int s0 = start[k], cnt = hist[k];
    double acc = 0.0;
    for (int i = sub; i < cnt; i += 4) {
        const int n = order[s0 + i];
        acc += (double)zf[(size_t)n * DD + d];   // 256 B contiguous per point
    }
    __shared__ double red[4][DD];
    red[sub][d] = acc;
    __syncthreads();
    if (sub == 0)
        esum[(size_t)k * DD + d] = (float)(red[0][d] + red[1][d] + red[2][d] + red[3][d]);
}

// ---------------- K3: EMA update + Laplace smoothing + new embedding ----------------
__global__ __launch_bounds__(1024) void vq_update(
    const float* __restrict__ cs, const int* __restrict__ hist,
    const float* __restrict__ avg, const float* __restrict__ esum,
    float* __restrict__ newE)
{
    __shared__ double red[KK];
    __shared__ float smo[KK];
    const int k = threadIdx.x;
    const double DECAY = 0.99, OMD = 1.0 - 0.99, EPSV = 1e-5;
    double ncs = DECAY * (double)cs[k] + OMD * (double)hist[k];
    red[k] = ncs;
    __syncthreads();
    for (int s = 512; s > 0; s >>= 1) {
        if (k < s) red[k] += red[k + s];
        __syncthreads();
    }
    double nsum = red[0];
    smo[k] = (float)((ncs + EPSV) / (nsum + (double)KK * EPSV) * nsum);
    __syncthreads();
    for (int it = 0; it < DD; ++it) {
        int j = it * KK + k;
        int kk = j >> 6;
        newE[j] = (float)((DECAY * (double)avg[j] + OMD * (double)esum[j]) / (double)smo[kk]);
    }
}

// ---------------- K4: gather z_q + commitment loss ----------------
__global__ __launch_bounds__(256) void vq_gather_loss(
    const float* __restrict__ z, const float* __restrict__ newE,
    const int* __restrict__ idx_ws, float* __restrict__ zq_out,
    double* __restrict__ loss_acc)
{
    const int tid = threadIdx.x;
    const int n = blockIdx.x * 256 + tid;
    const int b = n >> 12;
    const int t = n & 4095;
    const float* zb = z + ((size_t)b * DD) * TD + t;
    float* ob = zq_out + ((size_t)b * DD) * TD + t;
    const int bi = idx_ws[n];
    const float* e = newE + (size_t)bi * DD;
    double acc = 0.0;
#pragma unroll
    for (int d = 0; d < DD; ++d) {
        float q = e[d];
        float zv = zb[(size_t)d * TD];
        ob[(size_t)d * TD] = q;
        float df = zv - q;
        acc = fma((double)df, (double)df, acc);
    }
    for (int off = 32; off > 0; off >>= 1) acc += __shfl_down(acc, off, 64);
    __shared__ double wsum[4];
    const int wid = tid >> 6, lane = tid & 63;
    if (lane == 0) wsum[wid] = acc;
    __syncthreads();
    if (tid == 0) atomicAdd(loss_acc, wsum[0] + wsum[1] + wsum[2] + wsum[3]);
}

// ---------------- K5: finalize loss ----------------
__global__ void vq_finalize(const double* __restrict__ loss_acc, float* __restrict__ loss_out)
{
    *loss_out = (float)(0.25 * (*loss_acc) / (double)(N_PTS * DD));
}

extern "C" void kernel_launch(void* const* d_in, const int* in_sizes, int n_in,
                              void* d_out, int out_size, void* d_ws, size_t ws_size,
                              hipStream_t stream) {
    const float* z    = (const float*)d_in[0];   // [32, 64, 4096]
    const float* emb  = (const float*)d_in[1];   // [1024, 64]
    const float* cs   = (const float*)d_in[2];   // [1024]
    const float* avg  = (const float*)d_in[3];   // [1024, 64]

    float* out      = (float*)d_out;
    float* zq_out   = out;                // 8388608 floats (32 MB)
    float* loss_out = out + 8388608;      // 1
    float* ind_out  = out + 8388609;      // 131072 (indices as float)

    // z_flat[N][D] lives in the z_q region (dead before K4 rewrites it)
    float* zf = out;                      // 32 MB exactly

    char* ws = (char*)d_ws;
    int*    idx_ws   = (int*)ws;                     // 512 KB @ 0
    float*  newE     = (float*)(ws + 524288);        // 256 KB
    float*  esum     = (float*)(ws + 786432);        // 256 KB
    int*    hist     = (int*)(ws + 1048576);         // 4 KB   [memset]
    int*    nflag    = (int*)(ws + 1052672);         // 4 B    [memset]
    double* loss_acc = (double*)(ws + 1052680);      // 8 B    [memset]
    float*  halfnorm = (float*)(ws + 1052688);       // 4 KB
    int*    start    = (int*)(ws + 1056784);         // 4 KB
    int*    cursor   = (int*)(ws + 1060880);         // 4 KB
    int*    flags    = (int*)(ws + 1064976);         // 512 KB
    int*    order    = (int*)(ws + 1589264);         // 512 KB  (total ~2.02 MB)

    // zero hist + nflag + pad + loss_acc (contiguous 4112 B)
    hipMemsetAsync(ws + 1048576, 0, 4112, stream);

    vq_transpose<<<2048, 256, 0, stream>>>(z, zf);
    vq_norms<<<4, 256, 0, stream>>>(emb, halfnorm);
    vq_screen<<<N_PTS / 256, 256, 0, stream>>>(z, emb, halfnorm, idx_ws, ind_out, nflag, flags);
    vq_fallback<<<128, 256, 0, stream>>>(zf, emb, idx_ws, ind_out, nflag, flags);
    vq_hist<<<64, 256, 0, stream>>>(idx_ws, hist);
    vq_prefix<<<1, 1024, 0, stream>>>(hist, start, cursor);
    vq_scatter<<<N_PTS / 256, 256, 0, stream>>>(idx_ws, cursor, order);
    vq_esum<<<KK, 256, 0, stream>>>(zf, order, start, hist, esum);
    vq_update<<<1, 1024, 0, stream>>>(cs, hist, avg, esum, newE);
    vq_gather_loss<<<N_PTS / 256, 256, 0, stream>>>(z, newE, idx_ws, zq_out, loss_acc);
    vq_finalize<<<1, 1, 0, stream>>>(loss_acc, loss_out);
}

// Round 5
// 743.474 us; speedup vs baseline: 4.7688x; 1.3951x over previous
//
#include <hip/hip_runtime.h>

#define N_PTS 131072
#define TD 4096
#define DD 64
#define KK 1024
#define MARGIN_TH 2e-3f

typedef short bf16x8 __attribute__((ext_vector_type(8)));
typedef float f32x4  __attribute__((ext_vector_type(4)));

__device__ inline unsigned short f2bf(float f) {           // RNE float->bf16
    unsigned u = __float_as_uint(f);
    unsigned r = u + 0x7FFFu + ((u >> 16) & 1u);
    return (unsigned short)(r >> 16);
}
__device__ inline float bf2f(unsigned short h) {
    return __uint_as_float(((unsigned)h) << 16);
}

// ---------------- K0a: transpose z[B,D,T] -> z_hi/z_lo bf16 [N,D] ----------------
__global__ __launch_bounds__(256) void vq_prep(const float* __restrict__ z,
                                               unsigned short* __restrict__ zh,
                                               unsigned short* __restrict__ zl)
{
    __shared__ float tile[64][65];
    const int tid = threadIdx.x;
    const int lane = tid & 63;
    const int sub = tid >> 6;           // 0..3
    const int b = blockIdx.x >> 6;      // 32 b
    const int t0 = (blockIdx.x & 63) * 64;
#pragma unroll
    for (int i = 0; i < 16; ++i) {
        const int d = i * 4 + sub;
        tile[lane][d] = z[((size_t)b * DD + d) * TD + t0 + lane];
    }
    __syncthreads();
#pragma unroll
    for (int i = 0; i < 16; ++i) {
        const int tl = i * 4 + sub;
        const float v = tile[tl][lane];
        const unsigned short h = f2bf(v);
        const unsigned short l = f2bf(v - bf2f(h));
        const size_t o = ((size_t)(b * TD + t0 + tl)) * DD + lane;
        zh[o] = h;
        zl[o] = l;
    }
}

// ---------------- K0b: emb -> e_hi/e_lo bf16 + fp64-exact half norms ----------------
__global__ __launch_bounds__(256) void vq_eprep(const float* __restrict__ emb,
                                                unsigned short* __restrict__ eh,
                                                unsigned short* __restrict__ el,
                                                float* __restrict__ halfnorm)
{
    const int k = blockIdx.x * 256 + threadIdx.x;
    if (k >= KK) return;
    const float* e = emb + (size_t)k * DD;
    double s = 0.0;
#pragma unroll
    for (int d = 0; d < DD; ++d) {
        const float v = e[d];
        const double dv = (double)v;
        s = fma(dv, dv, s);
        const unsigned short h = f2bf(v);
        eh[(size_t)k * DD + d] = h;
        el[(size_t)k * DD + d] = f2bf(v - bf2f(h));
    }
    halfnorm[k] = (float)(0.5 * s);
}

// ---------------- K1: MFMA screen (bf16 hi/lo split), flag near-ties ----------------
__global__ __launch_bounds__(256) void vq_screen_mfma(
    const unsigned short* __restrict__ zh, const unsigned short* __restrict__ zl,
    const unsigned short* __restrict__ eh, const unsigned short* __restrict__ el,
    const float* __restrict__ hn,
    int* __restrict__ idx_ws, float* __restrict__ ind_out,
    int* __restrict__ nflag, int* __restrict__ flags)
{
    const int tid = threadIdx.x;
    const int lane = tid & 63;
    const int wid = tid >> 6;
    const int quad = lane >> 4;
    const int col = lane & 15;
    const int pbase = (blockIdx.x * 4 + wid) * 16;

    // A fragments: point = pbase+col, dims quad*8..+7 (and +32)
    const bf16x8* pAh = (const bf16x8*)(zh + (size_t)(pbase + col) * DD + quad * 8);
    const bf16x8* pAl = (const bf16x8*)(zl + (size_t)(pbase + col) * DD + quad * 8);
    const bf16x8 Ah0 = pAh[0], Ah1 = pAh[4];   // +4*8 ushorts = dims +32
    const bf16x8 Al0 = pAl[0], Al1 = pAl[4];

    float best[4]  = {1e30f, 1e30f, 1e30f, 1e30f};
    float best2[4] = {1e30f, 1e30f, 1e30f, 1e30f};
    int   bidx[4]  = {0, 0, 0, 0};

    for (int t = 0; t < KK / 16; ++t) {
        const size_t brow = (size_t)(t * 16 + col) * DD + quad * 8;
        const bf16x8 Bh0 = *(const bf16x8*)(eh + brow);
        const bf16x8 Bh1 = *(const bf16x8*)(eh + brow + 32);
        const bf16x8 Bl0 = *(const bf16x8*)(el + brow);
        const bf16x8 Bl1 = *(const bf16x8*)(el + brow + 32);
        const float hnv = hn[t * 16 + col];

        f32x4 acc = {0.f, 0.f, 0.f, 0.f};
        acc = __builtin_amdgcn_mfma_f32_16x16x32_bf16(Ah0, Bh0, acc, 0, 0, 0);
        acc = __builtin_amdgcn_mfma_f32_16x16x32_bf16(Ah1, Bh1, acc, 0, 0, 0);
        acc = __builtin_amdgcn_mfma_f32_16x16x32_bf16(Ah0, Bl0, acc, 0, 0, 0);
        acc = __builtin_amdgcn_mfma_f32_16x16x32_bf16(Ah1, Bl1, acc, 0, 0, 0);
        acc = __builtin_amdgcn_mfma_f32_16x16x32_bf16(Al0, Bh0, acc, 0, 0, 0);
        acc = __builtin_amdgcn_mfma_f32_16x16x32_bf16(Al1, Bh1, acc, 0, 0, 0);

        const int code = t * 16 + col;
#pragma unroll
        for (int r = 0; r < 4; ++r) {
            const float s = hnv - acc[r];
            const bool lt = s < best[r];
            best2[r] = fminf(best2[r], fmaxf(best[r], s));
            best[r] = lt ? s : best[r];
            bidx[r] = lt ? code : bidx[r];
        }
    }

    // merge across the 16 lanes of each quad-group (cols hold disjoint code sets)
#pragma unroll
    for (int off = 1; off < 16; off <<= 1) {
#pragma unroll
        for (int r = 0; r < 4; ++r) {
            const float ob  = __shfl_xor(best[r],  off, 64);
            const float ob2 = __shfl_xor(best2[r], off, 64);
            const int   oi  = __shfl_xor(bidx[r],  off, 64);
            const float nb2 = fminf(fminf(best2[r], ob2), fmaxf(best[r], ob));
            if (ob < best[r]) { best[r] = ob; bidx[r] = oi; }
            best2[r] = nb2;
        }
    }

    if (col == 0) {
#pragma unroll
        for (int r = 0; r < 4; ++r) {
            const int n = pbase + quad * 4 + r;
            idx_ws[n] = bidx[r];
            ind_out[n] = (float)bidx[r];
            if (best2[r] - best[r] < MARGIN_TH) {
                const int pos = atomicAdd(nflag, 1);
                flags[pos] = n;    // exact fp64 pass finalizes this point
            }
        }
    }
}

// ---------------- K1c: fp64 exact rescan for near-tie points (wave per point) ----------------
__global__ __launch_bounds__(256) void vq_fallback(
    const float* __restrict__ z, const float* __restrict__ emb,
    int* __restrict__ idx_ws, float* __restrict__ ind_out,
    const int* __restrict__ nflag, const int* __restrict__ flags)
{
    __shared__ float zs[4][DD];
    const int total = *nflag;
    const int lane = threadIdx.x & 63;
    const int wid = threadIdx.x >> 6;
    const int gw = blockIdx.x * 4 + wid;

    for (int i = gw; i < total; i += gridDim.x * 4) {
        const int n = flags[i];
        const int b = n >> 12, t = n & 4095;
        zs[wid][lane] = z[((size_t)b * DD + lane) * TD + t];
        __builtin_amdgcn_s_waitcnt(0);
        double best = 1e300;
        int bi = KK;
        for (int kc = 0; kc < KK / 64; ++kc) {
            const int k = kc * 64 + lane;
            const float4* e = (const float4*)(emb + (size_t)k * DD);
            double dot = 0.0, nn = 0.0;
#pragma unroll
            for (int j = 0; j < 16; ++j) {
                float4 ev = e[j];
                double e0 = (double)ev.x, e1 = (double)ev.y, e2 = (double)ev.z, e3 = (double)ev.w;
                nn = fma(e0, e0, fma(e1, e1, fma(e2, e2, fma(e3, e3, nn))));
                dot = fma((double)zs[wid][4 * j + 0], e0,
                      fma((double)zs[wid][4 * j + 1], e1,
                      fma((double)zs[wid][4 * j + 2], e2,
                      fma((double)zs[wid][4 * j + 3], e3, dot))));
            }
            double s = 0.5 * nn - dot;
            if (s < best || (s == best && k < bi)) { best = s; bi = k; }
        }
        for (int off = 32; off > 0; off >>= 1) {
            double os = __shfl_down(best, off, 64);
            int oi = __shfl_down(bi, off, 64);
            if (os < best || (os == best && oi < bi)) { best = os; bi = oi; }
        }
        if (lane == 0) { idx_ws[n] = bi; ind_out[n] = (float)bi; }
    }
}

// ---------------- K2a: histogram of final indices (LDS-privatized) ----------------
__global__ __launch_bounds__(256) void vq_hist(const int* __restrict__ idx_ws, int* __restrict__ hist)
{
    __shared__ int h[KK];
    for (int i = threadIdx.x; i < KK; i += 256) h[i] = 0;
    __syncthreads();
    const int base = blockIdx.x * 2048;
#pragma unroll
    for (int j = 0; j < 8; ++j)
        atomicAdd(&h[idx_ws[base + j * 256 + threadIdx.x]], 1);
    __syncthreads();
    for (int i = threadIdx.x; i < KK; i += 256)
        if (h[i]) atomicAdd(&hist[i], h[i]);
}

// ---------------- K2b: exclusive scan -> start/cursor ----------------
__global__ __launch_bounds__(1024) void vq_prefix(const int* __restrict__ hist,
                                                  int* __restrict__ start, int* __restrict__ cursor)
{
    __shared__ int tmp[KK];
    const int k = threadIdx.x;
    const int c = hist[k];
    tmp[k] = c;
    __syncthreads();
    for (int off = 1; off < KK; off <<= 1) {
        int u = (k >= off) ? tmp[k - off] : 0;
        __syncthreads();
        tmp[k] += u;
        __syncthreads();
    }
    const int s = tmp[k] - c;  // exclusive
    start[k] = s;
    cursor[k] = s;
}

// ---------------- K2c: scatter point ids into per-code lists ----------------
__global__ __launch_bounds__(256) void vq_scatter(const int* __restrict__ idx_ws,
                                                  int* __restrict__ cursor, int* __restrict__ order)
{
    const int n = blockIdx.x * 256 + threadIdx.x;
    const int bi = idx_ws[n];
    const int pos = atomicAdd(&cursor[bi], 1);
    order[pos] = n;
}

// ---------------- K2d: segment sum per code from z_hi+z_lo (block per code, fp64 acc) ----------------
__global__ __launch_bounds__(256) void vq_esum(
    const unsigned short* __restrict__ zh, const unsigned short* __restrict__ zl,
    const int* __restrict__ order,
    const int* __restrict__ start, const int* __restrict__ hist,
    float* __restrict__ esum)
{
    const int k = blockIdx.x;
    const int d = threadIdx.x & 63;
    const int sub = threadIdx.x >> 6;
    const int s0 = start[k], cnt = hist[k];
    double acc = 0.0;
    for (int i = sub; i < cnt; i += 4) {
        const int n = order[s0 + i];
        const size_t o = (size_t)n * DD + d;
        acc += (double)(bf2f(zh[o]) + bf2f(zl[o]));  // = z to 2^-18 rel
    }
    __shared__ double red[4][DD];
    red[sub][d] = acc;
    __syncthreads();
    if (sub == 0)
        esum[(size_t)k * DD + d] = (float)(red[0][d] + red[1][d] + red[2][d] + red[3][d]);
}

// ---------------- K3: EMA update + Laplace smoothing + new embedding ----------------
__global__ __launch_bounds__(1024) void vq_update(
    const float* __restrict__ cs, const int* __restrict__ hist,
    const float* __restrict__ avg, const float* __restrict__ esum,
    float* __restrict__ newE)
{
    __shared__ double red[KK];
    __shared__ float smo[KK];
    const int k = threadIdx.x;
    const double DECAY = 0.99, OMD = 1.0 - 0.99, EPSV = 1e-5;
    double ncs = DECAY * (double)cs[k] + OMD * (double)hist[k];
    red[k] = ncs;
    __syncthreads();
    for (int s = 512; s > 0; s >>= 1) {
        if (k < s) red[k] += red[k + s];
        __syncthreads();
    }
    double nsum = red[0];
    smo[k] = (float)((ncs + EPSV) / (nsum + (double)KK * EPSV) * nsum);
    __syncthreads();
    for (int it = 0; it < DD; ++it) {
        int j = it * KK + k;
        int kk = j >> 6;
        newE[j] = (float)((DECAY * (double)avg[j] + OMD * (double)esum[j]) / (double)smo[kk]);
    }
}

// ---------------- K4: gather z_q + commitment loss ----------------
__global__ __launch_bounds__(256) void vq_gather_loss(
    const float* __restrict__ z, const float* __restrict__ newE,
    const int* __restrict__ idx_ws, float* __restrict__ zq_out,
    double* __restrict__ loss_acc)
{
    const int tid = threadIdx.x;
    const int n = blockIdx.x * 256 + tid;
    const int b = n >> 12;
    const int t = n & 4095;
    const float* zb = z + ((size_t)b * DD) * TD + t;
    float* ob = zq_out + ((size_t)b * DD) * TD + t;
    const int bi = idx_ws[n];
    const float* e = newE + (size_t)bi * DD;
    double acc = 0.0;
#pragma unroll
    for (int d = 0; d < DD; ++d) {
        float q = e[d];
        float zv = zb[(size_t)d * TD];
        ob[(size_t)d * TD] = q;
        float df = zv - q;
        acc = fma((double)df, (double)df, acc);
    }
    for (int off = 32; off > 0; off >>= 1) acc += __shfl_down(acc, off, 64);
    __shared__ double wsum[4];
    const int wid = tid >> 6, lane = tid & 63;
    if (lane == 0) wsum[wid] = acc;
    __syncthreads();
    if (tid == 0) atomicAdd(loss_acc, wsum[0] + wsum[1] + wsum[2] + wsum[3]);
}

// ---------------- K5: finalize loss ----------------
__global__ void vq_finalize(const double* __restrict__ loss_acc, float* __restrict__ loss_out)
{
    *loss_out = (float)(0.25 * (*loss_acc) / (double)(N_PTS * DD));
}

extern "C" void kernel_launch(void* const* d_in, const int* in_sizes, int n_in,
                              void* d_out, int out_size, void* d_ws, size_t ws_size,
                              hipStream_t stream) {
    const float* z    = (const float*)d_in[0];   // [32, 64, 4096]
    const float* emb  = (const float*)d_in[1];   // [1024, 64]
    const float* cs   = (const float*)d_in[2];   // [1024]
    const float* avg  = (const float*)d_in[3];   // [1024, 64]

    float* out      = (float*)d_out;
    float* zq_out   = out;                // 8388608 floats (32 MiB)
    float* loss_out = out + 8388608;      // 1
    float* ind_out  = out + 8388609;      // 131072 (indices as float)

    // z_hi/z_lo bf16 [N][D] exactly fill the z_q region (dead before K4 rewrites it)
    unsigned short* zh = (unsigned short*)d_out;                       // 16 MiB
    unsigned short* zl = (unsigned short*)((char*)d_out + 16777216);   // 16 MiB

    char* ws = (char*)d_ws;
    int*            idx_ws   = (int*)ws;                     // 512 KB @ 0
    float*          newE     = (float*)(ws + 524288);        // 256 KB
    float*          esum     = (float*)(ws + 786432);        // 256 KB
    int*            hist     = (int*)(ws + 1048576);         // 4 KB   [memset]
    int*            nflag    = (int*)(ws + 1052672);         // 4 B    [memset]
    double*         loss_acc = (double*)(ws + 1052680);      // 8 B    [memset]
    float*          halfnorm = (float*)(ws + 1052688);       // 4 KB
    int*            start    = (int*)(ws + 1056784);         // 4 KB
    int*            cursor   = (int*)(ws + 1060880);         // 4 KB
    int*            flags    = (int*)(ws + 1064976);         // 512 KB
    int*            order    = (int*)(ws + 1589264);         // 512 KB
    unsigned short* eh       = (unsigned short*)(ws + 2113552); // 128 KB
    unsigned short* el       = (unsigned short*)(ws + 2244624); // 128 KB (~2.37 MB total)

    // zero hist + nflag + pad + loss_acc (contiguous 4112 B)
    hipMemsetAsync(ws + 1048576, 0, 4112, stream);

    vq_prep<<<2048, 256, 0, stream>>>(z, zh, zl);
    vq_eprep<<<4, 256, 0, stream>>>(emb, eh, el, halfnorm);
    vq_screen_mfma<<<2048, 256, 0, stream>>>(zh, zl, eh, el, halfnorm,
                                             idx_ws, ind_out, nflag, flags);
    vq_fallback<<<128, 256, 0, stream>>>(z, emb, idx_ws, ind_out, nflag, flags);
    vq_hist<<<64, 256, 0, stream>>>(idx_ws, hist);
    vq_prefix<<<1, 1024, 0, stream>>>(hist, start, cursor);
    vq_scatter<<<N_PTS / 256, 256, 0, stream>>>(idx_ws, cursor, order);
    vq_esum<<<KK, 256, 0, stream>>>(zh, zl, order, start, hist, esum);
    vq_update<<<1, 1024, 0, stream>>>(cs, hist, avg, esum, newE);
    vq_gather_loss<<<N_PTS / 256, 256, 0, stream>>>(z, newE, idx_ws, zq_out, loss_acc);
    vq_finalize<<<1, 1, 0, stream>>>(loss_acc, loss_out);
}

// Round 6
// 619.892 us; speedup vs baseline: 5.7195x; 1.1994x over previous
//
#include <hip/hip_runtime.h>

#define N_PTS 131072
#define TD 4096
#define DD 64
#define KK 1024
#define MARGIN_TH 2e-3f

typedef short bf16x8 __attribute__((ext_vector_type(8)));
typedef float f32x4  __attribute__((ext_vector_type(4)));

__device__ inline unsigned short f2bf(float f) {           // RNE float->bf16
    unsigned u = __float_as_uint(f);
    unsigned r = u + 0x7FFFu + ((u >> 16) & 1u);
    return (unsigned short)(r >> 16);
}
__device__ inline float bf2f(unsigned short h) {
    return __uint_as_float(((unsigned)h) << 16);
}

// ---------------- K0a: transpose z[B,D,T] -> z_hi/z_lo bf16 [N,D] ----------------
__global__ __launch_bounds__(256) void vq_prep(const float* __restrict__ z,
                                               unsigned short* __restrict__ zh,
                                               unsigned short* __restrict__ zl)
{
    __shared__ float tile[64][65];
    const int tid = threadIdx.x;
    const int lane = tid & 63;
    const int sub = tid >> 6;           // 0..3
    const int b = blockIdx.x >> 6;      // 32 b
    const int t0 = (blockIdx.x & 63) * 64;
#pragma unroll
    for (int i = 0; i < 16; ++i) {
        const int d = i * 4 + sub;
        tile[lane][d] = z[((size_t)b * DD + d) * TD + t0 + lane];
    }
    __syncthreads();
#pragma unroll
    for (int i = 0; i < 16; ++i) {
        const int tl = i * 4 + sub;
        const float v = tile[tl][lane];
        const unsigned short h = f2bf(v);
        const unsigned short l = f2bf(v - bf2f(h));
        const size_t o = ((size_t)(b * TD + t0 + tl)) * DD + lane;
        zh[o] = h;
        zl[o] = l;
    }
}

// ---------------- K0b: emb -> e_hi/e_lo bf16 + fp64-exact half norms ----------------
__global__ __launch_bounds__(256) void vq_eprep(const float* __restrict__ emb,
                                                unsigned short* __restrict__ eh,
                                                unsigned short* __restrict__ el,
                                                float* __restrict__ halfnorm)
{
    const int k = blockIdx.x * 256 + threadIdx.x;
    if (k >= KK) return;
    const float* e = emb + (size_t)k * DD;
    double s = 0.0;
#pragma unroll
    for (int d = 0; d < DD; ++d) {
        const float v = e[d];
        const double dv = (double)v;
        s = fma(dv, dv, s);
        const unsigned short h = f2bf(v);
        eh[(size_t)k * DD + d] = h;
        el[(size_t)k * DD + d] = f2bf(v - bf2f(h));
    }
    halfnorm[k] = (float)(0.5 * s);
}

// ---------------- K1: MFMA screen, 32 pts/wave, B double-buffered ----------------
__global__ __launch_bounds__(256, 3) void vq_screen_mfma(
    const unsigned short* __restrict__ zh, const unsigned short* __restrict__ zl,
    const unsigned short* __restrict__ eh, const unsigned short* __restrict__ el,
    const float* __restrict__ hn,
    int* __restrict__ idx_ws, float* __restrict__ ind_out,
    int* __restrict__ nflag, int* __restrict__ flags)
{
    const int tid = threadIdx.x;
    const int lane = tid & 63;
    const int wid = tid >> 6;
    const int quad = lane >> 4;
    const int col = lane & 15;
    const int pbase = (blockIdx.x * 4 + wid) * 32;   // 32 points per wave

    // A fragments: tile0 = points pbase..+15, tile1 = +16..+31; dims quad*8..+7 / +32
    const bf16x8* pA0h = (const bf16x8*)(zh + (size_t)(pbase + col) * DD + quad * 8);
    const bf16x8* pA0l = (const bf16x8*)(zl + (size_t)(pbase + col) * DD + quad * 8);
    const bf16x8* pA1h = (const bf16x8*)(zh + (size_t)(pbase + 16 + col) * DD + quad * 8);
    const bf16x8* pA1l = (const bf16x8*)(zl + (size_t)(pbase + 16 + col) * DD + quad * 8);
    const bf16x8 A0h0 = pA0h[0], A0h1 = pA0h[4];
    const bf16x8 A0l0 = pA0l[0], A0l1 = pA0l[4];
    const bf16x8 A1h0 = pA1h[0], A1h1 = pA1h[4];
    const bf16x8 A1l0 = pA1l[0], A1l1 = pA1l[4];

    float best0[4]  = {1e30f, 1e30f, 1e30f, 1e30f};
    float best20[4] = {1e30f, 1e30f, 1e30f, 1e30f};
    int   bidx0[4]  = {0, 0, 0, 0};
    float best1[4]  = {1e30f, 1e30f, 1e30f, 1e30f};
    float best21[4] = {1e30f, 1e30f, 1e30f, 1e30f};
    int   bidx1[4]  = {0, 0, 0, 0};

    // prime B double-buffer (t = 0)
    size_t brow = (size_t)col * DD + quad * 8;
    bf16x8 Bh0 = *(const bf16x8*)(eh + brow);
    bf16x8 Bh1 = *(const bf16x8*)(eh + brow + 32);
    bf16x8 Bl0 = *(const bf16x8*)(el + brow);
    bf16x8 Bl1 = *(const bf16x8*)(el + brow + 32);
    float hnv = hn[col];

    for (int t = 0; t < KK / 16; ++t) {
        // prefetch next tile's B fragments ((t+1)&63 wraps harmlessly at the end)
        const int tn = (t + 1) & 63;
        const size_t nrow = (size_t)(tn * 16 + col) * DD + quad * 8;
        const bf16x8 nBh0 = *(const bf16x8*)(eh + nrow);
        const bf16x8 nBh1 = *(const bf16x8*)(eh + nrow + 32);
        const bf16x8 nBl0 = *(const bf16x8*)(el + nrow);
        const bf16x8 nBl1 = *(const bf16x8*)(el + nrow + 32);
        const float nhn = hn[tn * 16 + col];

        // 4 independent 3-chains (2 per point-tile)
        f32x4 p0 = {0.f, 0.f, 0.f, 0.f}, q0 = {0.f, 0.f, 0.f, 0.f};
        f32x4 p1 = {0.f, 0.f, 0.f, 0.f}, q1 = {0.f, 0.f, 0.f, 0.f};
        p0 = __builtin_amdgcn_mfma_f32_16x16x32_bf16(A0h0, Bh0, p0, 0, 0, 0);
        p1 = __builtin_amdgcn_mfma_f32_16x16x32_bf16(A1h0, Bh0, p1, 0, 0, 0);
        q0 = __builtin_amdgcn_mfma_f32_16x16x32_bf16(A0l0, Bh0, q0, 0, 0, 0);
        q1 = __builtin_amdgcn_mfma_f32_16x16x32_bf16(A1l0, Bh0, q1, 0, 0, 0);
        p0 = __builtin_amdgcn_mfma_f32_16x16x32_bf16(A0h1, Bh1, p0, 0, 0, 0);
        p1 = __builtin_amdgcn_mfma_f32_16x16x32_bf16(A1h1, Bh1, p1, 0, 0, 0);
        q0 = __builtin_amdgcn_mfma_f32_16x16x32_bf16(A0l1, Bh1, q0, 0, 0, 0);
        q1 = __builtin_amdgcn_mfma_f32_16x16x32_bf16(A1l1, Bh1, q1, 0, 0, 0);
        p0 = __builtin_amdgcn_mfma_f32_16x16x32_bf16(A0h0, Bl0, p0, 0, 0, 0);
        p1 = __builtin_amdgcn_mfma_f32_16x16x32_bf16(A1h0, Bl0, p1, 0, 0, 0);
        q0 = __builtin_amdgcn_mfma_f32_16x16x32_bf16(A0h1, Bl1, q0, 0, 0, 0);
        q1 = __builtin_amdgcn_mfma_f32_16x16x32_bf16(A1h1, Bl1, q1, 0, 0, 0);

        const int code = t * 16 + col;
#pragma unroll
        for (int r = 0; r < 4; ++r) {
            const float s0 = hnv - (p0[r] + q0[r]);
            const bool l0 = s0 < best0[r];
            best20[r] = fminf(best20[r], fmaxf(best0[r], s0));
            best0[r] = l0 ? s0 : best0[r];
            bidx0[r] = l0 ? code : bidx0[r];
            const float s1 = hnv - (p1[r] + q1[r]);
            const bool l1 = s1 < best1[r];
            best21[r] = fminf(best21[r], fmaxf(best1[r], s1));
            best1[r] = l1 ? s1 : best1[r];
            bidx1[r] = l1 ? code : bidx1[r];
        }

        Bh0 = nBh0; Bh1 = nBh1; Bl0 = nBl0; Bl1 = nBl1; hnv = nhn;
    }

    // merge across the 16 cols of each quad-group (disjoint code sets)
#pragma unroll
    for (int off = 1; off < 16; off <<= 1) {
#pragma unroll
        for (int r = 0; r < 4; ++r) {
            {
                const float ob  = __shfl_xor(best0[r],  off, 64);
                const float ob2 = __shfl_xor(best20[r], off, 64);
                const int   oi  = __shfl_xor(bidx0[r],  off, 64);
                const float nb2 = fminf(fminf(best20[r], ob2), fmaxf(best0[r], ob));
                if (ob < best0[r]) { best0[r] = ob; bidx0[r] = oi; }
                best20[r] = nb2;
            }
            {
                const float ob  = __shfl_xor(best1[r],  off, 64);
                const float ob2 = __shfl_xor(best21[r], off, 64);
                const int   oi  = __shfl_xor(bidx1[r],  off, 64);
                const float nb2 = fminf(fminf(best21[r], ob2), fmaxf(best1[r], ob));
                if (ob < best1[r]) { best1[r] = ob; bidx1[r] = oi; }
                best21[r] = nb2;
            }
        }
    }

    if (col == 0) {
#pragma unroll
        for (int r = 0; r < 4; ++r) {
            const int n0 = pbase + quad * 4 + r;
            idx_ws[n0] = bidx0[r];
            ind_out[n0] = (float)bidx0[r];
            if (best20[r] - best0[r] < MARGIN_TH) {
                const int pos = atomicAdd(nflag, 1);
                flags[pos] = n0;
            }
            const int n1 = pbase + 16 + quad * 4 + r;
            idx_ws[n1] = bidx1[r];
            ind_out[n1] = (float)bidx1[r];
            if (best21[r] - best1[r] < MARGIN_TH) {
                const int pos = atomicAdd(nflag, 1);
                flags[pos] = n1;
            }
        }
    }
}

// ---------------- K1c: fp64 exact rescan for near-tie points (wave per point) ----------------
__global__ __launch_bounds__(256) void vq_fallback(
    const float* __restrict__ z, const float* __restrict__ emb,
    int* __restrict__ idx_ws, float* __restrict__ ind_out,
    const int* __restrict__ nflag, const int* __restrict__ flags)
{
    __shared__ float zs[4][DD];
    const int total = *nflag;
    const int lane = threadIdx.x & 63;
    const int wid = threadIdx.x >> 6;
    const int gw = blockIdx.x * 4 + wid;

    for (int i = gw; i < total; i += gridDim.x * 4) {
        const int n = flags[i];
        const int b = n >> 12, t = n & 4095;
        zs[wid][lane] = z[((size_t)b * DD + lane) * TD + t];
        __builtin_amdgcn_s_waitcnt(0);
        double best = 1e300;
        int bi = KK;
        for (int kc = 0; kc < KK / 64; ++kc) {
            const int k = kc * 64 + lane;
            const float4* e = (const float4*)(emb + (size_t)k * DD);
            double dot = 0.0, nn = 0.0;
#pragma unroll
            for (int j = 0; j < 16; ++j) {
                float4 ev = e[j];
                double e0 = (double)ev.x, e1 = (double)ev.y, e2 = (double)ev.z, e3 = (double)ev.w;
                nn = fma(e0, e0, fma(e1, e1, fma(e2, e2, fma(e3, e3, nn))));
                dot = fma((double)zs[wid][4 * j + 0], e0,
                      fma((double)zs[wid][4 * j + 1], e1,
                      fma((double)zs[wid][4 * j + 2], e2,
                      fma((double)zs[wid][4 * j + 3], e3, dot))));
            }
            double s = 0.5 * nn - dot;
            if (s < best || (s == best && k < bi)) { best = s; bi = k; }
        }
        for (int off = 32; off > 0; off >>= 1) {
            double os = __shfl_down(best, off, 64);
            int oi = __shfl_down(bi, off, 64);
            if (os < best || (os == best && oi < bi)) { best = os; bi = oi; }
        }
        if (lane == 0) { idx_ws[n] = bi; ind_out[n] = (float)bi; }
    }
}

// ---------------- K2a: histogram of final indices (LDS-privatized) ----------------
__global__ __launch_bounds__(256) void vq_hist(const int* __restrict__ idx_ws, int* __restrict__ hist)
{
    __shared__ int h[KK];
    for (int i = threadIdx.x; i < KK; i += 256) h[i] = 0;
    __syncthreads();
    const int base = blockIdx.x * 2048;
#pragma unroll
    for (int j = 0; j < 8; ++j)
        atomicAdd(&h[idx_ws[base + j * 256 + threadIdx.x]], 1);
    __syncthreads();
    for (int i = threadIdx.x; i < KK; i += 256)
        if (h[i]) atomicAdd(&hist[i], h[i]);
}

// ---------------- K2b: exclusive scan -> start/cursor ----------------
__global__ __launch_bounds__(1024) void vq_prefix(const int* __restrict__ hist,
                                                  int* __restrict__ start, int* __restrict__ cursor)
{
    __shared__ int tmp[KK];
    const int k = threadIdx.x;
    const int c = hist[k];
    tmp[k] = c;
    __syncthreads();
    for (int off = 1; off < KK; off <<= 1) {
        int u = (k >= off) ? tmp[k - off] : 0;
        __syncthreads();
        tmp[k] += u;
        __syncthreads();
    }
    const int s = tmp[k] - c;  // exclusive
    start[k] = s;
    cursor[k] = s;
}

// ---------------- K2c: scatter point ids into per-code lists ----------------
__global__ __launch_bounds__(256) void vq_scatter(const int* __restrict__ idx_ws,
                                                  int* __restrict__ cursor, int* __restrict__ order)
{
    const int n = blockIdx.x * 256 + threadIdx.x;
    const int bi = idx_ws[n];
    const int pos = atomicAdd(&cursor[bi], 1);
    order[pos] = n;
}

// ---------------- K2d: segment sum per code from z_hi+z_lo (block per code, fp64 acc) ----------------
__global__ __launch_bounds__(256) void vq_esum(
    const unsigned short* __restrict__ zh, const unsigned short* __restrict__ zl,
    const int* __restrict__ order,
    const int* __restrict__ start, const int* __restrict__ hist,
    float* __restrict__ esum)
{
    const int k = blockIdx.x;
    const int d = threadIdx.x & 63;
    const int sub = threadIdx.x >> 6;
    const int s0 = start[k], cnt = hist[k];
    double acc = 0.0;
    for (int i = sub; i < cnt; i += 4) {
        const int n = order[s0 + i];
        const size_t o = (size_t)n * DD + d;
        acc += (double)(bf2f(zh[o]) + bf2f(zl[o]));  // = z to 2^-18 rel
    }
    __shared__ double red[4][DD];
    red[sub][d] = acc;
    __syncthreads();
    if (sub == 0)
        esum[(size_t)k * DD + d] = (float)(red[0][d] + red[1][d] + red[2][d] + red[3][d]);
}

// ---------------- K3: EMA update + Laplace smoothing + new embedding ----------------
__global__ __launch_bounds__(1024) void vq_update(
    const float* __restrict__ cs, const int* __restrict__ hist,
    const float* __restrict__ avg, const float* __restrict__ esum,
    float* __restrict__ newE)
{
    __shared__ double red[KK];
    __shared__ float smo[KK];
    const int k = threadIdx.x;
    const double DECAY = 0.99, OMD = 1.0 - 0.99, EPSV = 1e-5;
    double ncs = DECAY * (double)cs[k] + OMD * (double)hist[k];
    red[k] = ncs;
    __syncthreads();
    for (int s = 512; s > 0; s >>= 1) {
        if (k < s) red[k] += red[k + s];
        __syncthreads();
    }
    double nsum = red[0];
    smo[k] = (float)((ncs + EPSV) / (nsum + (double)KK * EPSV) * nsum);
    __syncthreads();
    for (int it = 0; it < DD; ++it) {
        int j = it * KK + k;
        int kk = j >> 6;
        newE[j] = (float)((DECAY * (double)avg[j] + OMD * (double)esum[j]) / (double)smo[kk]);
    }
}

// ---------------- K4: gather z_q + commitment loss (finalize fused) ----------------
__global__ __launch_bounds__(256) void vq_gather_loss(
    const float* __restrict__ z, const float* __restrict__ newE,
    const int* __restrict__ idx_ws, float* __restrict__ zq_out,
    double* __restrict__ loss_acc, int* __restrict__ done_cnt,
    float* __restrict__ loss_out)
{
    const int tid = threadIdx.x;
    const int n = blockIdx.x * 256 + tid;
    const int b = n >> 12;
    const int t = n & 4095;
    const float* zb = z + ((size_t)b * DD) * TD + t;
    float* ob = zq_out + ((size_t)b * DD) * TD + t;
    const int bi = idx_ws[n];
    const float* e = newE + (size_t)bi * DD;
    double acc = 0.0;
#pragma unroll
    for (int d = 0; d < DD; ++d) {
        float q = e[d];
        float zv = zb[(size_t)d * TD];
        ob[(size_t)d * TD] = q;
        float df = zv - q;
        acc = fma((double)df, (double)df, acc);
    }
    for (int off = 32; off > 0; off >>= 1) acc += __shfl_down(acc, off, 64);
    __shared__ double wsum[4];
    const int wid = tid >> 6, lane = tid & 63;
    if (lane == 0) wsum[wid] = acc;
    __syncthreads();
    if (tid == 0) {
        atomicAdd(loss_acc, wsum[0] + wsum[1] + wsum[2] + wsum[3]);
        __threadfence();
        const int prev = atomicAdd(done_cnt, 1);
        if (prev == gridDim.x - 1) {
            __threadfence();
            *loss_out = (float)(0.25 * (*loss_acc) / (double)(N_PTS * DD));
        }
    }
}

extern "C" void kernel_launch(void* const* d_in, const int* in_sizes, int n_in,
                              void* d_out, int out_size, void* d_ws, size_t ws_size,
                              hipStream_t stream) {
    const float* z    = (const float*)d_in[0];   // [32, 64, 4096]
    const float* emb  = (const float*)d_in[1];   // [1024, 64]
    const float* cs   = (const float*)d_in[2];   // [1024]
    const float* avg  = (const float*)d_in[3];   // [1024, 64]

    float* out      = (float*)d_out;
    float* zq_out   = out;                // 8388608 floats (32 MiB)
    float* loss_out = out + 8388608;      // 1
    float* ind_out  = out + 8388609;      // 131072 (indices as float)

    // z_hi/z_lo bf16 [N][D] exactly fill the z_q region (dead before K4 rewrites it)
    unsigned short* zh = (unsigned short*)d_out;                       // 16 MiB
    unsigned short* zl = (unsigned short*)((char*)d_out + 16777216);   // 16 MiB

    char* ws = (char*)d_ws;
    int*            idx_ws   = (int*)ws;                     // 512 KB @ 0
    float*          newE     = (float*)(ws + 524288);        // 256 KB
    float*          esum     = (float*)(ws + 786432);        // 256 KB
    int*            hist     = (int*)(ws + 1048576);         // 4 KB   [memset]
    int*            nflag    = (int*)(ws + 1052672);         // 4 B    [memset]
    int*            done_cnt = (int*)(ws + 1052676);         // 4 B    [memset]
    double*         loss_acc = (double*)(ws + 1052680);      // 8 B    [memset]
    float*          halfnorm = (float*)(ws + 1052688);       // 4 KB
    int*            start    = (int*)(ws + 1056784);         // 4 KB
    int*            cursor   = (int*)(ws + 1060880);         // 4 KB
    int*            flags    = (int*)(ws + 1064976);         // 512 KB
    int*            order    = (int*)(ws + 1589264);         // 512 KB
    unsigned short* eh       = (unsigned short*)(ws + 2113552); // 128 KB
    unsigned short* el       = (unsigned short*)(ws + 2244624); // 128 KB

    // zero hist + nflag + done_cnt + loss_acc (contiguous 4112 B)
    hipMemsetAsync(ws + 1048576, 0, 4112, stream);

    vq_prep<<<2048, 256, 0, stream>>>(z, zh, zl);
    vq_eprep<<<4, 256, 0, stream>>>(emb, eh, el, halfnorm);
    vq_screen_mfma<<<1024, 256, 0, stream>>>(zh, zl, eh, el, halfnorm,
                                             idx_ws, ind_out, nflag, flags);
    vq_fallback<<<128, 256, 0, stream>>>(z, emb, idx_ws, ind_out, nflag, flags);
    vq_hist<<<64, 256, 0, stream>>>(idx_ws, hist);
    vq_prefix<<<1, 1024, 0, stream>>>(hist, start, cursor);
    vq_scatter<<<N_PTS / 256, 256, 0, stream>>>(idx_ws, cursor, order);
    vq_esum<<<KK, 256, 0, stream>>>(zh, zl, order, start, hist, esum);
    vq_update<<<1, 1024, 0, stream>>>(cs, hist, avg, esum, newE);
    vq_gather_loss<<<N_PTS / 256, 256, 0, stream>>>(z, newE, idx_ws, zq_out,
                                                    loss_acc, done_cnt, loss_out);
}